// Round 3
// baseline (30.889 us; speedup 1.0000x reference)
//
#include <hip/hip_runtime.h>

// Problem geometry (fixed by reference setup_inputs)
#define B  4
#define D  48
#define H  128
#define W  240
#define H4 512   // 4*H
#define W4 960   // 4*W
#define TS 16    // coarse tile side; grid = (W/TS)*(H/TS)*B = 15*8*4 = 480 blocks

// Fused: phase A computes 18x18 halo'd top-2 soft-argmax disp into LDS,
// phase B does 3x3 unfold + 4x nearest upsample + spg-weighted sum, *4.
__global__ void __launch_bounds__(256)
fused_disp_upfeat_kernel(const float* __restrict__ cost,
                         const float* __restrict__ spg,
                         float* __restrict__ out) {
    __shared__ float sd[TS + 2][TS + 3];   // 18 x 19 (pad to spread banks)

    int blk = blockIdx.x;
    int txt = blk % (W / TS);
    int rem = blk / (W / TS);
    int tyt = rem % (H / TS);
    int b   = rem / (H / TS);
    int x0  = txt * TS - 1;                // halo origin (coarse coords)
    int y0  = tyt * TS - 1;

    // ---- Phase A: 324 disp values, 256 threads (2nd pass covers 68) ----
    for (int i = threadIdx.x; i < (TS + 2) * (TS + 2); i += 256) {
        int iy = i / (TS + 2);
        int ix = i - iy * (TS + 2);
        int y  = y0 + iy;
        int x  = x0 + ix;
        float dres = 0.0f;                 // zero-pad outside image
        if ((unsigned)x < W && (unsigned)y < H) {
            const float* p = cost + (size_t)b * (D * H * W) + y * W + x;
            float v[D];
            #pragma unroll
            for (int d = 0; d < D; ++d) v[d] = p[(size_t)d * (H * W)];
            float v1 = -INFINITY, v2 = -INFINITY;
            int   i1 = 0,          i2 = 0;
            #pragma unroll
            for (int d = 0; d < D; ++d) {
                float xv = v[d];
                if (xv > v1)      { v2 = v1; i2 = i1; v1 = xv; i1 = d; }
                else if (xv > v2) { v2 = xv; i2 = d; }
            }
            float e = expf(v2 - v1);
            dres = ((float)i1 + (float)i2 * e) / (1.0f + e);
        }
        sd[iy][ix] = dres;
    }
    __syncthreads();

    // ---- Phase B: one coarse pixel per thread -> 4 rows x float4 outputs ----
    int t  = threadIdx.x;
    int cx = t & (TS - 1);
    int cy = t >> 4;

    float dv[9];
    #pragma unroll
    for (int dy = 0; dy < 3; ++dy)
        #pragma unroll
        for (int dx = 0; dx < 3; ++dx)
            dv[dy * 3 + dx] = sd[cy + dy][cx + dx];

    int xs  = x0 + 1 + cx;                 // global coarse x in [0,W)
    int Yb  = (y0 + 1 + cy) * 4;           // fine base row

    #pragma unroll
    for (int r = 0; r < 4; ++r) {
        int Y = Yb + r;
        const float* sp = spg + ((size_t)(b * 9) * H4 + Y) * W4 + xs * 4;
        float4 acc = make_float4(0.f, 0.f, 0.f, 0.f);
        #pragma unroll
        for (int k = 0; k < 9; ++k) {
            float4 s = *reinterpret_cast<const float4*>(sp + (size_t)k * (H4 * W4));
            float  d = dv[k];
            acc.x += d * s.x; acc.y += d * s.y; acc.z += d * s.z; acc.w += d * s.w;
        }
        acc.x *= 4.f; acc.y *= 4.f; acc.z *= 4.f; acc.w *= 4.f;
        *reinterpret_cast<float4*>(out + ((size_t)b * H4 + Y) * W4 + xs * 4) = acc;
    }
}

extern "C" void kernel_launch(void* const* d_in, const int* in_sizes, int n_in,
                              void* d_out, int out_size, void* d_ws, size_t ws_size,
                              hipStream_t stream) {
    const float* cost = (const float*)d_in[0];   // [B,1,D,H,W]
    const float* spg  = (const float*)d_in[1];   // [B,9,H4,W4]
    float* outp = (float*)d_out;                 // [B,H4,W4]

    const int nblk = (W / TS) * (H / TS) * B;    // 480
    fused_disp_upfeat_kernel<<<nblk, 256, 0, stream>>>(cost, spg, outp);
}

// Round 4
// 23.695 us; speedup vs baseline: 1.3036x; 1.3036x over previous
//
#include <hip/hip_runtime.h>

// Problem geometry (fixed by reference setup_inputs)
#define B  4
#define D  48
#define H  128
#define W  240
#define H4 512   // 4*H
#define W4 960   // 4*W
#define DSPLIT 2           // threads per pixel in kernel 1
#define DPART  (D / DSPLIT)

// Kernel 1: top-2 soft-argmax over D, 2 threads per pixel (24 d-slices each),
// merged with one shfl_xor. Doubles TLP vs the 1-thread/pixel version, which
// was latency-bound at 480 blocks (measured ~2.4 TB/s effective).
__global__ void __launch_bounds__(256)
topk_softargmax_kernel(const float* __restrict__ cost, float* __restrict__ disp4) {
    int gid = blockIdx.x * blockDim.x + threadIdx.x;
    const int nthreads = B * H * W * DSPLIT;
    if (gid >= nthreads) return;
    int pix  = gid >> 1;
    int half = gid & 1;
    int b    = pix / (H * W);
    int rem  = pix - b * (H * W);              // y*W + x
    const float* p = cost + (size_t)b * (D * H * W)
                          + (size_t)(half * DPART) * (H * W) + rem;

    float v[DPART];
    #pragma unroll
    for (int d = 0; d < DPART; ++d) v[d] = p[(size_t)d * (H * W)];

    float v1 = -INFINITY, v2 = -INFINITY;
    int   i1 = 0,          i2 = 0;
    const int d0 = half * DPART;
    #pragma unroll
    for (int d = 0; d < DPART; ++d) {
        float x = v[d];
        if (x > v1)      { v2 = v1; i2 = i1; v1 = x; i1 = d0 + d; }
        else if (x > v2) { v2 = x;  i2 = d0 + d; }
    }

    // merge partner's top-2 (partner = lane^1, same pixel, other D half)
    float pv1 = __shfl_xor(v1, 1);
    int   pi1 = __shfl_xor(i1, 1);
    float pv2 = __shfl_xor(v2, 1);
    int   pi2 = __shfl_xor(i2, 1);

    // a = low-index half, bb = high-index half (for lowest-index tie-break)
    float av1, av2, bv1, bv2; int ai1, ai2, bi1, bi2;
    if (half == 0) { av1=v1;  ai1=i1;  av2=v2;  ai2=i2;  bv1=pv1; bi1=pi1; bv2=pv2; bi2=pi2; }
    else           { av1=pv1; ai1=pi1; av2=pv2; ai2=pi2; bv1=v1;  bi1=i1;  bv2=v2;  bi2=i2; }

    float t1v, t2v; int t1i, t2i;
    if (bv1 > av1) {          // top1 from high half
        t1v = bv1; t1i = bi1;
        if (av1 >= bv2) { t2v = av1; t2i = ai1; } else { t2v = bv2; t2i = bi2; }
    } else {                  // top1 from low half (ties -> low index)
        t1v = av1; t1i = ai1;
        if (av2 >= bv1) { t2v = av2; t2i = ai2; } else { t2v = bv1; t2i = bi1; }
    }

    if (half == 0) {
        float e   = expf(t2v - t1v);
        disp4[pix] = ((float)t1i + (float)t2i * e) / (1.0f + e);
    }
}

// Kernel 2: 3x3 unfold (zero pad) + nearest 4x upsample + weighted sum by spg, *4.
// One thread -> 4 consecutive output pixels (same coarse source pixel).
// spg layout: [B,9,H4,W4]; out layout: [B,H4,W4]
__global__ void __launch_bounds__(256)
upfeat_kernel(const float* __restrict__ disp4, const float* __restrict__ spg,
              float* __restrict__ out) {
    int t = blockIdx.x * blockDim.x + threadIdx.x;
    const int nt = B * H4 * W;   // W = W4/4 thread-groups per row
    if (t >= nt) return;

    int xs  = t % W;
    int tmp = t / W;
    int Y   = tmp % H4;
    int b   = tmp / H4;
    int y   = Y >> 2;

    // 3x3 disp neighborhood (zero outside)
    float dv[9];
    const float* dp = disp4 + (size_t)b * (H * W);
    #pragma unroll
    for (int dy = 0; dy < 3; ++dy) {
        int yy = y + dy - 1;
        #pragma unroll
        for (int dx = 0; dx < 3; ++dx) {
            int xx = xs + dx - 1;
            dv[dy * 3 + dx] = (yy >= 0 && yy < H && xx >= 0 && xx < W)
                              ? dp[yy * W + xx] : 0.0f;
        }
    }

    const float* sp = spg + (((size_t)b * 9) * H4 + Y) * W4 + 4 * xs;
    float4 acc = make_float4(0.f, 0.f, 0.f, 0.f);
    #pragma unroll
    for (int k = 0; k < 9; ++k) {
        float4 s = *reinterpret_cast<const float4*>(sp + (size_t)k * (H4 * W4));
        float  d = dv[k];
        acc.x += d * s.x; acc.y += d * s.y; acc.z += d * s.z; acc.w += d * s.w;
    }
    acc.x *= 4.f; acc.y *= 4.f; acc.z *= 4.f; acc.w *= 4.f;

    *reinterpret_cast<float4*>(out + ((size_t)b * H4 + Y) * W4 + 4 * xs) = acc;
}

extern "C" void kernel_launch(void* const* d_in, const int* in_sizes, int n_in,
                              void* d_out, int out_size, void* d_ws, size_t ws_size,
                              hipStream_t stream) {
    const float* cost = (const float*)d_in[0];   // [B,1,D,H,W]
    const float* spg  = (const float*)d_in[1];   // [B,9,H4,W4]
    float* outp  = (float*)d_out;                // [B,H4,W4]
    float* disp4 = (float*)d_ws;                 // [B,H,W] scratch (491 KB)

    {
        const int n = B * H * W * DSPLIT;        // 245760 threads, 960 blocks
        topk_softargmax_kernel<<<(n + 255) / 256, 256, 0, stream>>>(cost, disp4);
    }
    {
        const int n = B * H4 * W;                // 491520 threads, 1920 blocks
        upfeat_kernel<<<(n + 255) / 256, 256, 0, stream>>>(disp4, spg, outp);
    }
}